// Round 4
// baseline (236.084 us; speedup 1.0000x reference)
//
#include <hip/hip_runtime.h>
#include <stdint.h>

// Problem constants (reference: B=2, D=128, H=64, W=64)
#define BN 2
#define DN 128
#define MN 4096                          // H*W pixels per image
#define TOTAL_INV (1.0f / 33554432.0f)   // 1 / (B*M*N)
#define NT 64                            // 64x64 tiles per side: MN/64
#define NBLK (NT * NT)                   // 4096 tiles per image
#define PARTIALS (NBLK * BN)             // 8192 per-block partial sums

typedef __attribute__((ext_vector_type(8))) short short8;   // 8 bf16 = 4 VGPRs
typedef __attribute__((ext_vector_type(4))) float f32x4;

__device__ static inline unsigned short f2bf(float x) {
  // round-to-nearest-even f32 -> bf16 (inputs are finite normals)
  unsigned int u = __float_as_uint(x);
  u += 0x7fffu + ((u >> 16) & 1u);
  return (unsigned short)(u >> 16);
}

__device__ static inline void async16(const void* g, void* l) {
  // 16B global -> LDS direct copy (dest = wave-uniform base + lane*16)
  __builtin_amdgcn_global_load_lds(
      (const __attribute__((address_space(1))) void*)g,
      (__attribute__((address_space(3))) void*)l, 16, 0, 0);
}

// [B, D, M] f32  ->  [B, M, D] bf16(ushort), 64x64 LDS tile transpose (proven)
__global__ __launch_bounds__(256) void transpose_cvt(
    const float* __restrict__ s0, const float* __restrict__ s1,
    unsigned short* __restrict__ o0, unsigned short* __restrict__ o1) {
  __shared__ float tile[64][65];          // +1 pad: conflict-free transpose
  const int tx = threadIdx.x & 63;
  const int ty = threadIdx.x >> 6;        // 0..3 (wave id)
  const int m0 = blockIdx.x * 64;
  const int d0 = blockIdx.y * 64;
  const int b  = blockIdx.z & 1;
  const float* src = (blockIdx.z >> 1) ? s1 : s0;
  unsigned short* dst = (blockIdx.z >> 1) ? o1 : o0;
  src += (size_t)b * DN * MN;
  dst += (size_t)b * MN * DN;
#pragma unroll
  for (int i = 0; i < 16; ++i) {
    int dr = i * 4 + ty;
    tile[dr][tx] = src[(size_t)(d0 + dr) * MN + m0 + tx];  // 256B coalesced / wave
  }
  __syncthreads();
#pragma unroll
  for (int i = 0; i < 16; ++i) {
    int mr = i * 4 + ty;
    dst[(size_t)(m0 + mr) * DN + d0 + tx] = f2bf(tile[tx][mr]);  // 128B coalesced
  }
}

// v3: barrier-free 1-wave blocks. Each wave owns a 64x64 output tile, loads its
// MFMA fragments DIRECTLY global->VGPR (no LDS panels, no __syncthreads, no
// vmcnt(0) drains in the hot path). 4-KB u8 mask tile staged via global_load_lds
// at wave start (issued first, consumed last -> latency fully hidden).
// Per-block partial sum stored to ws (no same-address atomic storm).
// grid: (4096, B), block: 64 (one wave)
__global__ __launch_bounds__(64) void gemm_loss(
    const unsigned short* __restrict__ A, const unsigned short* __restrict__ Bm,
    const void* __restrict__ maskp, float* __restrict__ partial) {
  __shared__ __align__(16) unsigned char Ms[64 * 64];   // 4 KB mask tile

  const int lane = threadIdx.x;
  const int quad = lane >> 4;
  const int l16  = lane & 15;
  const int wgid = blockIdx.x;
  const int bz   = blockIdx.y;

  // XCD-bijective swizzle (4096 % 8 == 0): each XCD sweeps bn with bm fixed for
  // 64 consecutive blocks -> A-panel (32 KB) L2-hot; B (2 MB) fits per-XCD L2.
  const int swz = (wgid & 7) * (NBLK / 8) + (wgid >> 3);
  const int bm = swz >> 6;
  const int bn = swz & 63;

  // ---- mask dtype sniff: int32 {0,1} has zero bytes at offset%4!=0 ----
  const unsigned int sd = ((const unsigned int*)maskp)[lane];
  const int u8 = (__ballot((int)(sd & 0xFFFFFF00u)) != 0ull);  // wave-uniform

  // issue the 4-KB mask tile first: flows under the entire K-loop
  const unsigned char* mg = (const unsigned char*)maskp +
      ((size_t)bz * MN + (size_t)bm * 64) * MN + (size_t)bn * 64;
  if (u8) {
#pragma unroll
    for (int p = 0; p < 4; ++p) {
      int c = p * 64 + lane;             // row = c>>2, 16B col chunk = (c&3)*16
      async16(mg + (size_t)(c >> 2) * MN + (c & 3) * 16, Ms + c * 16);
    }
  }

  const unsigned short* Ab = A  + ((size_t)bz * MN + (size_t)bm * 64) * DN;
  const unsigned short* Bb = Bm + ((size_t)bz * MN + (size_t)bn * 64) * DN;

  f32x4 acc[4][4];
#pragma unroll
  for (int i = 0; i < 4; ++i)
#pragma unroll
    for (int j = 0; j < 4; ++j) acc[i][j] = (f32x4){0.f, 0.f, 0.f, 0.f};

  // K-loop: direct global->VGPR fragments (A-frag layout identical to the
  // verified LDS version: lane(q,l) reads row mi*16+l16, k = kt*32 + q*8).
#pragma unroll
  for (int kt = 0; kt < 4; ++kt) {
    short8 af[4], bf[4];
#pragma unroll
    for (int mi = 0; mi < 4; ++mi)
      af[mi] = *(const short8*)(Ab + (size_t)(mi * 16 + l16) * DN + kt * 32 + quad * 8);
#pragma unroll
    for (int ni = 0; ni < 4; ++ni)
      bf[ni] = *(const short8*)(Bb + (size_t)(ni * 16 + l16) * DN + kt * 32 + quad * 8);
#pragma unroll
    for (int mi = 0; mi < 4; ++mi)
#pragma unroll
      for (int ni = 0; ni < 4; ++ni)
        acc[mi][ni] = __builtin_amdgcn_mfma_f32_16x16x32_bf16(
            af[mi], bf[ni], acc[mi][ni], 0, 0, 0);
  }

  // all global_load_lds mask writes landed (frag loads are done anyway via deps)
  asm volatile("s_waitcnt vmcnt(0)" ::: "memory");

  // ---- epilogue: hinge loss under mask, wave reduction, one partial store ----
  // C/D layout: col = lane&15 (n), row = quad*4 + r (m)
  const size_t gbase =
      ((size_t)bz * MN + (size_t)bm * 64) * MN + (size_t)bn * 64;
  const int* mi32 = (const int*)maskp;
  float lsum = 0.0f;
#pragma unroll
  for (int mi = 0; mi < 4; ++mi) {
#pragma unroll
    for (int ni = 0; ni < 4; ++ni) {
      f32x4 v = acc[mi][ni];
#pragma unroll
      for (int r = 0; r < 4; ++r) {
        int m = mi * 16 + quad * 4 + r;
        int n = ni * 16 + l16;
        int msk = u8 ? (int)Ms[m * 64 + n]
                     : mi32[gbase + (size_t)m * MN + n];
        float dot = v[r];
        float pos = fmaxf(0.0f, 1.0f - dot) * 250.0f;
        float neg = fmaxf(0.0f, dot - 0.2f);
        lsum += msk ? pos : neg;
      }
    }
  }
#pragma unroll
  for (int off = 32; off > 0; off >>= 1) lsum += __shfl_xor(lsum, off);
  if (lane == 0) partial[(size_t)bz * NBLK + wgid] = lsum;  // plain store, no atomic
}

// Final reduction: 8192 partials -> out[0]. One block, ~32 KB read.
__global__ __launch_bounds__(256) void reduce_partials(
    const float* __restrict__ p, float* __restrict__ out) {
  __shared__ float red[4];
  const int tid = threadIdx.x;
  float s = 0.0f;
  for (int i = tid; i < PARTIALS; i += 256) s += p[i];
#pragma unroll
  for (int off = 32; off > 0; off >>= 1) s += __shfl_xor(s, off);
  if ((tid & 63) == 0) red[tid >> 6] = s;
  __syncthreads();
  if (tid == 0) out[0] = (red[0] + red[1] + red[2] + red[3]) * TOTAL_INV;
}

extern "C" void kernel_launch(void* const* d_in, const int* in_sizes, int n_in,
                              void* d_out, int out_size, void* d_ws, size_t ws_size,
                              hipStream_t stream) {
  const float* d0 = (const float*)d_in[0];
  const float* d1 = (const float*)d_in[1];
  const void* mask = d_in[2];
  float* out = (float*)d_out;

  unsigned short* Aw = (unsigned short*)d_ws;            // [B, M, D] bf16, 2 MB
  unsigned short* Bw = Aw + (size_t)BN * MN * DN;        // [B, M, D] bf16, 2 MB
  float* partial = (float*)((char*)d_ws + (8u << 20));   // 32 KB at +8 MB

  dim3 g1(MN / 64, DN / 64, BN * 2), b1(256);
  transpose_cvt<<<g1, b1, 0, stream>>>(d0, d1, Aw, Bw);

  dim3 g2(NBLK, BN), b2(64);
  gemm_loss<<<g2, b2, 0, stream>>>(Aw, Bw, mask, partial);

  reduce_partials<<<1, 256, 0, stream>>>(partial, out);  // writes out directly
}

// Round 5
// 213.762 us; speedup vs baseline: 1.1044x; 1.1044x over previous
//
#include <hip/hip_runtime.h>
#include <stdint.h>

// Problem constants (reference: B=2, D=128, H=64, W=64)
#define BN 2
#define DN 128
#define MN 4096                          // H*W pixels per image
#define TOTAL_INV (1.0f / 33554432.0f)   // 1 / (B*M*N)
#define NTILE 32                         // 128x128 tiles per side
#define NBLK (NTILE * NTILE)             // 1024 tiles per image
#define PARTIALS (NBLK * BN)             // 2048 per-block partials
#define KSLAB ((size_t)MN * 32)          // elems per [kt] slab of one image

typedef __attribute__((ext_vector_type(8))) short short8;   // 8 bf16 = 4 VGPRs
typedef __attribute__((ext_vector_type(4))) float f32x4;
typedef __attribute__((ext_vector_type(4))) unsigned int u32x4;

__device__ static inline unsigned short f2bf(float x) {
  // round-to-nearest-even f32 -> bf16 (inputs are finite normals)
  unsigned int u = __float_as_uint(x);
  u += 0x7fffu + ((u >> 16) & 1u);
  return (unsigned short)(u >> 16);
}

__device__ static inline void async16(const void* g, void* l) {
  // 16B global -> LDS direct copy (dest = wave-uniform base + lane*16)
  __builtin_amdgcn_global_load_lds(
      (const __attribute__((address_space(1))) void*)g,
      (__attribute__((address_space(3))) void*)l, 16, 0, 0);
}

// prep kernel: bid < 1024 -> mask repack stripe; bid >= 1024 -> transpose tile.
// Mask repack: linear 32-KB stripe read -> LDS reshuffle -> tile-ordered 1-KB
// chunk writes. Kills the 64-B x 4-KB-stride scatter that capped HBM at ~1 TB/s.
// Transpose: [B,D,M] f32 -> kt-blocked [b][kt][m][32] bf16 so GEMM staging is
// fully contiguous per K-step.
__global__ __launch_bounds__(256) void prep(
    const float* __restrict__ s0, const float* __restrict__ s1,
    const void* __restrict__ maskp,
    unsigned short* __restrict__ o0, unsigned short* __restrict__ o1,
    unsigned char* __restrict__ tmask) {
  __shared__ __align__(16) unsigned char sh[32 * 1040];  // 33,280 B (union use)
  __shared__ int flag;
  const int tid = threadIdx.x;
  const int bid = blockIdx.x;

  if (bid < 1024) {
    // ---- mask repack: 8-row stripe of one image ----
    // dtype sniff: int32 {0,1} has zero bytes at offset%4!=0
    if (tid == 0) flag = 0;
    __syncthreads();
    if (((const unsigned int*)maskp)[tid] & 0xFFFFFF00u) flag = 1;  // benign race
    __syncthreads();
    if (!flag) return;                    // i32 mask: gemm uses the global path

    const int bz = bid >> 9;              // 512 stripes per image
    const int m0 = (bid & 511) * 8;
    const unsigned char* src =
        (const unsigned char*)maskp + ((size_t)bz * MN + m0) * MN;
    // phase 1: read 8 x 4096 B linear (fully coalesced), store LDS in out-order
    // LDS chunk c (n>>7) = 1024 B data + 16 B pad -> ds_write 2-way max
#pragma unroll
    for (int row = 0; row < 8; ++row) {
      u32x4 v = *(const u32x4*)(src + (size_t)row * MN + tid * 16);
      int c  = tid >> 3;                  // (tid*16)>>7
      int nc = (tid & 7) * 16;
      *(u32x4*)(sh + c * 1040 + row * 128 + nc) = v;
    }
    __syncthreads();
    // phase 2: write 32 chunks of 1024 B, each contiguous in its dest tile
    const int bm = m0 >> 7, r0 = m0 & 127;
    unsigned char* ob =
        tmask + ((size_t)(bz * NBLK + bm * NTILE)) * 16384 + r0 * 128;
#pragma unroll
    for (int it = 0; it < 8; ++it) {
      int c = it * 4 + (tid >> 6);        // chunk 0..31
      int inner = (tid & 63) * 16;
      u32x4 v = *(const u32x4*)(sh + c * 1040 + inner);
      *(u32x4*)(ob + (size_t)c * 16384 + inner) = v;
    }
  } else {
    // ---- 64x64 f32->bf16 transpose tile (proven), kt-blocked output ----
    float (*tile)[65] = (float(*)[65])sh;   // 16,640 B <= 33,280
    const int t  = bid - 1024;
    const int m0 = (t & 63) * 64;
    const int d0 = ((t >> 6) & 1) * 64;
    const int img = t >> 7;               // 0..3
    const int b = img & 1;
    const float* src = (img >> 1) ? s1 : s0;
    unsigned short* dst = (img >> 1) ? o1 : o0;
    src += (size_t)b * DN * MN;
    dst += (size_t)b * 4 * KSLAB;         // image base in [b][kt][m][32]
    const int tx = tid & 63;
    const int ty = tid >> 6;
#pragma unroll
    for (int i = 0; i < 16; ++i) {
      int dr = i * 4 + ty;
      tile[dr][tx] = src[(size_t)(d0 + dr) * MN + m0 + tx];  // 256B/wave coalesced
    }
    __syncthreads();
    const int d = d0 + tx;
    const size_t dbase = (size_t)(d >> 5) * MN * 32 + (d & 31);
#pragma unroll
    for (int i = 0; i < 16; ++i) {
      int mr = i * 4 + ty;
      dst[dbase + (size_t)(m0 + mr) * 32] = f2bf(tile[tx][mr]);  // 64B runs
    }
  }
}

// Fused bf16 MFMA GEMM (C = A * B^T) + hinge loss + mean partial.
// All HBM traffic contiguous: 8-KB panel slabs per kt + 16-KB tiled mask run.
// Double-buffered (stage t+1 || compute t); buffer index = kt & 1 (r3 fix).
// grid: (32, 32, B), block 256 (4 waves, 2x2; each wave 64x64 = 4x4 MFMAs)
__global__ __launch_bounds__(256) void gemm_loss(
    const unsigned short* __restrict__ A, const unsigned short* __restrict__ Bm,
    const void* __restrict__ maskp, const unsigned char* __restrict__ tmask,
    float* __restrict__ partial) {
  __shared__ __align__(16) unsigned short As[2][128 * 32];  // 2 x 8 KB
  __shared__ __align__(16) unsigned short Bs[2][128 * 32];  // 2 x 8 KB
  __shared__ __align__(16) unsigned char Ms[128 * 128];     // 16 KB mask tile
  __shared__ float red[4];
  __shared__ int mask_is_u8;

  const int tid  = threadIdx.x;
  const int lane = tid & 63;
  const int wave = tid >> 6;
  const int wm = wave >> 1, wn = wave & 1;
  const int quad = lane >> 4;
  const int l16  = lane & 15;
  const int bn = blockIdx.x, bm = blockIdx.y, bz = blockIdx.z;

  if (tid == 0) mask_is_u8 = 0;
  __syncthreads();
  if (((const unsigned int*)maskp)[tid] & 0xFFFFFF00u) mask_is_u8 = 1;  // benign race

  const unsigned short* Abase = A  + (size_t)bz * 4 * KSLAB + (size_t)(bm * 128) * 32;
  const unsigned short* Bbase = Bm + (size_t)bz * 4 * KSLAB + (size_t)(bn * 128) * 32;

  f32x4 acc[4][4];
#pragma unroll
  for (int i = 0; i < 4; ++i)
#pragma unroll
    for (int j = 0; j < 4; ++j) acc[i][j] = (f32x4){0.f, 0.f, 0.f, 0.f};

  // stage one 8-KB contiguous slab per matrix (LDS image = linear copy)
  auto stage = [&](int sel, int kt) {
    const unsigned short* Ak = Abase + (size_t)kt * KSLAB;
    const unsigned short* Bk = Bbase + (size_t)kt * KSLAB;
#pragma unroll
    for (int p = 0; p < 2; ++p) {
      int c = tid + p * 256;              // 512 x 16-B chunks, fully linear
      async16(Ak + c * 8, &As[sel][c * 8]);
      async16(Bk + c * 8, &Bs[sel][c * 8]);
    }
  };
  auto compute = [&](int sel) {           // sel = BUFFER index (0 or 1)
    short8 af[4], bf[4];
#pragma unroll
    for (int mi = 0; mi < 4; ++mi)        // ds_read_b128, [m][32k] layout unchanged
      af[mi] = *(const short8*)(&As[sel][(wm * 64 + mi * 16 + l16) * 32 + quad * 8]);
#pragma unroll
    for (int ni = 0; ni < 4; ++ni)
      bf[ni] = *(const short8*)(&Bs[sel][(wn * 64 + ni * 16 + l16) * 32 + quad * 8]);
#pragma unroll
    for (int mi = 0; mi < 4; ++mi)
#pragma unroll
      for (int ni = 0; ni < 4; ++ni)
        acc[mi][ni] = __builtin_amdgcn_mfma_f32_16x16x32_bf16(
            af[mi], bf[ni], acc[mi][ni], 0, 0, 0);
  };

  stage(0, 0);
  __syncthreads();                        // kt0 ready; sniff flag uniform
  const int u8 = mask_is_u8;

  // stage the block's 16-KB tiled mask (ONE contiguous run) under the K-loop
  if (u8) {
    const unsigned char* mt =
        tmask + (size_t)(bz * NBLK + bm * NTILE + bn) * 16384;
#pragma unroll
    for (int p = 0; p < 4; ++p) {
      int c = tid + p * 256;
      async16(mt + c * 16, Ms + c * 16);
    }
  }
  stage(1, 1);
  compute(0);                             // kt0 from buf0
  __syncthreads();
  stage(0, 2);
  compute(1);                             // kt1 from buf1
  __syncthreads();
  stage(1, 3);
  compute(0);                             // kt2 from buf0
  __syncthreads();
  compute(1);                             // kt3 from buf1

  // ---- epilogue: hinge loss under mask, block reduction, partial store ----
  // C/D layout: col = lane&15 (n), row = quad*4 + r (m)   [wave-relative 64x64]
  const size_t gbase =
      ((size_t)bz * MN + (size_t)(bm * 128 + wm * 64)) * MN + (size_t)(bn * 128 + wn * 64);
  const int* mi32 = (const int*)maskp;
  const int lrow0 = wm * 64, lcol0 = wn * 64;
  float lsum = 0.0f;
#pragma unroll
  for (int mi = 0; mi < 4; ++mi) {
#pragma unroll
    for (int ni = 0; ni < 4; ++ni) {
      f32x4 v = acc[mi][ni];
#pragma unroll
      for (int r = 0; r < 4; ++r) {
        int m = mi * 16 + quad * 4 + r;
        int n = ni * 16 + l16;
        int msk = u8 ? (int)Ms[(lrow0 + m) * 128 + lcol0 + n]
                     : mi32[gbase + (size_t)m * MN + n];
        float dot = v[r];
        float pos = fmaxf(0.0f, 1.0f - dot) * 250.0f;
        float neg = fmaxf(0.0f, dot - 0.2f);
        lsum += msk ? pos : neg;
      }
    }
  }
#pragma unroll
  for (int off = 32; off > 0; off >>= 1) lsum += __shfl_xor(lsum, off);
  if (lane == 0) red[wave] = lsum;
  __syncthreads();
  if (tid == 0)
    partial[bz * NBLK + bm * NTILE + bn] = red[0] + red[1] + red[2] + red[3];
}

// Final reduction: 2048 partials -> out[0] (full overwrite, no memset needed)
__global__ __launch_bounds__(256) void reduce_partials(
    const float* __restrict__ p, float* __restrict__ out) {
  __shared__ float red[4];
  const int tid = threadIdx.x;
  float s = 0.0f;
  for (int i = tid; i < PARTIALS; i += 256) s += p[i];
#pragma unroll
  for (int off = 32; off > 0; off >>= 1) s += __shfl_xor(s, off);
  if ((tid & 63) == 0) red[tid >> 6] = s;
  __syncthreads();
  if (tid == 0) out[0] = (red[0] + red[1] + red[2] + red[3]) * TOTAL_INV;
}

extern "C" void kernel_launch(void* const* d_in, const int* in_sizes, int n_in,
                              void* d_out, int out_size, void* d_ws, size_t ws_size,
                              hipStream_t stream) {
  const float* d0 = (const float*)d_in[0];
  const float* d1 = (const float*)d_in[1];
  const void* mask = d_in[2];
  float* out = (float*)d_out;

  // ws layout: A (2 MB) | B (2 MB) | tiled mask (33.5 MB @ +4 MB) | partials @ +40 MB
  unsigned short* Aw = (unsigned short*)d_ws;            // [B][kt][M][32] bf16
  unsigned short* Bw = Aw + (size_t)BN * 4 * KSLAB;
  unsigned char* tmask = (unsigned char*)d_ws + (4u << 20);
  float* partial = (float*)((char*)d_ws + (40u << 20));

  dim3 g1(1024 + 512), b1(256);           // 1024 mask stripes + 512 transpose tiles
  prep<<<g1, b1, 0, stream>>>(d0, d1, mask, Aw, Bw, tmask);

  dim3 g2(NTILE, NTILE, BN), b2(256);
  gemm_loss<<<g2, b2, 0, stream>>>(Aw, Bw, mask, tmask, partial);

  reduce_partials<<<1, 256, 0, stream>>>(partial, out);
}